// Round 7
// baseline (83.032 us; speedup 1.0000x reference)
//
#include <hip/hip_runtime.h>
#include <hip/hip_bf16.h>
#include <math.h>

#define BATCH 4
#define CDIM 256
#define NDIM 4096
#define CLD 32
#define EPSBN 1e-5f
#define SPLITS 8
#define KEYS_PER_WAVE (NDIM / SPLITS)   // 512
#define LOG2E 1.4426950408889634f
#define DEFER_THR 8.0f
#define NT (NDIM / 32)                  // 128 key-tiles per batch

typedef unsigned short u16;
typedef unsigned int u32;
typedef __attribute__((ext_vector_type(8))) short bf16x8;   // 8 bf16 = 4 VGPR MFMA operand
typedef __attribute__((ext_vector_type(16))) float f32x16;  // 32x32 MFMA accumulator
typedef __attribute__((ext_vector_type(4))) u32 u32x4;

__device__ inline u16 f2bf(float x) {
    return __builtin_bit_cast(u16, __float2bfloat16(x));
}
__device__ inline u32 pack_bf16x2(float a, float b) {
    return (u32)f2bf(a) | ((u32)f2bf(b) << 16);
}
__device__ inline float bfbits2f(u16 u) {
    return __builtin_bit_cast(float, (u32)u << 16);
}

// ---------------- Kernel 1: QKV projection + BN + ReLU -> bf16 ----------------
// grid (N/64, B, 3), block 256 = 4 waves (3 waves/SIMD total). Wave g = z*4+w
// owns 8 channels of one of {w1,w2,w3} x 64 n (1 n/lane). Weights via uniform
// s_load; x via coalesced dword loads.
// q (scaled by log2e), k -> [B][N][32] bf16.
// v -> tiled [B][N/32][32 d][32 slot] bf16, slot = kappa(key&31) so attention's
// PV A-operand loads are contiguous like K (kappa: p^=12 if ((p>>2)&3) in {1,2}).
__global__ __launch_bounds__(256) void proj_qkv(
    const float* __restrict__ x,
    const float* __restrict__ w1, const float* __restrict__ w2, const float* __restrict__ w3,
    const float* __restrict__ b1s, const float* __restrict__ b1b, const float* __restrict__ b1m, const float* __restrict__ b1v,
    const float* __restrict__ b2s, const float* __restrict__ b2b, const float* __restrict__ b2m, const float* __restrict__ b2v,
    const float* __restrict__ b3s, const float* __restrict__ b3b, const float* __restrict__ b3m, const float* __restrict__ b3v,
    u16* __restrict__ qo, u16* __restrict__ ko, u16* __restrict__ vo)
{
    const int tid  = threadIdx.x;
    const int lane = tid & 63;
    const int b    = blockIdx.y;
    const int g    = __builtin_amdgcn_readfirstlane(blockIdx.z * 4 + (tid >> 6)); // 0..11 uniform
    const int mat  = g >> 2;             // 0:q/w1 1:k/w2 2:v/w3
    const int ch0  = (g & 3) * 8;
    const int n    = blockIdx.x * 64 + lane;

    const float* wb = ((mat == 0) ? w1 : (mat == 1) ? w2 : w3) + (size_t)ch0 * CDIM;

    float acc[8];
#pragma unroll
    for (int o = 0; o < 8; ++o) acc[o] = 0.f;

    const float* xb = x + (size_t)b * CDIM * NDIM + n;

#pragma unroll 4
    for (int c = 0; c < CDIM; c += 4) {
        float4 wq[8];
#pragma unroll
        for (int o = 0; o < 8; ++o)
            wq[o] = *reinterpret_cast<const float4*>(wb + o * CDIM + c);  // uniform -> s_load
        float xv[4];
#pragma unroll
        for (int cc = 0; cc < 4; ++cc)
            xv[cc] = xb[(size_t)(c + cc) * NDIM];
#pragma unroll
        for (int cc = 0; cc < 4; ++cc) {
#pragma unroll
            for (int o = 0; o < 8; ++o) {
                float wv = (cc == 0) ? wq[o].x : (cc == 1) ? wq[o].y : (cc == 2) ? wq[o].z : wq[o].w;
                acc[o] = fmaf(wv, xv[cc], acc[o]);
            }
        }
    }

    const float* ps = (mat == 0) ? b1s : (mat == 1) ? b2s : b3s;
    const float* pb = (mat == 0) ? b1b : (mat == 1) ? b2b : b3b;
    const float* pm = (mat == 0) ? b1m : (mat == 1) ? b2m : b3m;
    const float* pv = (mat == 0) ? b1v : (mat == 1) ? b2v : b3v;
    const float qscale = (mat == 0) ? LOG2E : 1.0f;

    float y0[8];
#pragma unroll
    for (int o = 0; o < 8; ++o) {
        float inv = ps[ch0 + o] / sqrtf(pv[ch0 + o] + EPSBN);
        y0[o] = fmaxf((acc[o] - pm[ch0 + o]) * inv + pb[ch0 + o], 0.f) * qscale;
    }

    if (mat < 2) {
        u16* dst = ((mat == 0) ? qo : ko) + ((size_t)b * NDIM + n) * CLD + ch0;
        u32x4 s0;
        s0.x = pack_bf16x2(y0[0], y0[1]); s0.y = pack_bf16x2(y0[2], y0[3]);
        s0.z = pack_bf16x2(y0[4], y0[5]); s0.w = pack_bf16x2(y0[6], y0[7]);
        *reinterpret_cast<u32x4*>(dst) = s0;
    } else {
        // tiled + kappa slot
        int t = n >> 5;
        int p = n & 31;
        int q2 = (p >> 2) & 3;
        if (q2 == 1 || q2 == 2) p ^= 12;
        u16* base = vo + ((size_t)(b * NT + t) * 32) * 32 + p;
#pragma unroll
        for (int o = 0; o < 8; ++o)
            base[(ch0 + o) * 32] = f2bf(y0[o]);
    }
}

// ---------------- Kernel 2: MFMA flash attention, 8-way split-in-block ----------------
// grid (N/32, B), block 512 = 8 waves; all waves share one 32-query tile, each
// owns 512 keys. Scores in log2 domain (q pre-scaled by log2e). V is tiled +
// kappa-permuted so P fragments come directly from accumulator registers and
// V loads are contiguous. Defer-max THR=8 skips identity O-rescales.
// LDS combine writes agg bf16 [B][N][32].
__global__ __launch_bounds__(512, 4) void attn_mfma(
    const u16* __restrict__ q, const u16* __restrict__ k, const u16* __restrict__ v,
    u16* __restrict__ agg)
{
    __shared__ float o_lds[SPLITS][32][32];   // 32 KB
    __shared__ float m_lds[SPLITS][32];
    __shared__ float l_lds[SPLITS][32];

    const int tid  = threadIdx.x;
    const int lane = tid & 63;
    const int w    = tid >> 6;            // split 0..7
    const int b    = blockIdx.y;
    const int q0   = blockIdx.x * 32;
    const int col  = lane & 31;
    const int hi   = lane >> 5;

    const u16* qp = q + ((size_t)b * NDIM + q0 + col) * CLD + 8 * hi;
    bf16x8 qf0 = *reinterpret_cast<const bf16x8*>(qp);
    bf16x8 qf1 = *reinterpret_cast<const bf16x8*>(qp + 16);

    f32x16 o = {0.f,0.f,0.f,0.f, 0.f,0.f,0.f,0.f, 0.f,0.f,0.f,0.f, 0.f,0.f,0.f,0.f};
    float m_run = -3e38f, l_run = 0.f;

    const int kstart = w * KEYS_PER_WAVE;
    const u16* kb = k + (size_t)b * NDIM * CLD;
    const u16* vb = v + (size_t)(b * NT) * 1024 + (size_t)col * 32 + 8 * hi;

    for (int kt = 0; kt < KEYS_PER_WAVE; kt += 64) {
        const int k0 = kstart + kt;
        // ---- loads for two 32-key tiles (issued together, consumed apart) ----
        const u16* kpA = kb + (size_t)(k0 + col) * CLD + 8 * hi;
        bf16x8 kfA0 = *reinterpret_cast<const bf16x8*>(kpA);
        bf16x8 kfA1 = *reinterpret_cast<const bf16x8*>(kpA + 16);
        const u16* kpB = kpA + 32 * CLD;
        bf16x8 kfB0 = *reinterpret_cast<const bf16x8*>(kpB);
        bf16x8 kfB1 = *reinterpret_cast<const bf16x8*>(kpB + 16);

        const u16* vp = vb + (size_t)(k0 >> 5) * 1024;
        bf16x8 vfA0 = *reinterpret_cast<const bf16x8*>(vp);
        bf16x8 vfA1 = *reinterpret_cast<const bf16x8*>(vp + 16);
        bf16x8 vfB0 = *reinterpret_cast<const bf16x8*>(vp + 1024);
        bf16x8 vfB1 = *reinterpret_cast<const bf16x8*>(vp + 1040);

        f32x16 sa = {0.f,0.f,0.f,0.f, 0.f,0.f,0.f,0.f, 0.f,0.f,0.f,0.f, 0.f,0.f,0.f,0.f};
        f32x16 sb = {0.f,0.f,0.f,0.f, 0.f,0.f,0.f,0.f, 0.f,0.f,0.f,0.f, 0.f,0.f,0.f,0.f};
        sa = __builtin_amdgcn_mfma_f32_32x32x16_bf16(kfA0, qf0, sa, 0, 0, 0);
        sa = __builtin_amdgcn_mfma_f32_32x32x16_bf16(kfA1, qf1, sa, 0, 0, 0);
        sb = __builtin_amdgcn_mfma_f32_32x32x16_bf16(kfB0, qf0, sb, 0, 0, 0);
        sb = __builtin_amdgcn_mfma_f32_32x32x16_bf16(kfB1, qf1, sb, 0, 0, 0);

        // ---- online softmax over 64 keys (log2 domain, defer-max THR=8) ----
        float tmax = fmaxf(sa[0], sb[0]);
#pragma unroll
        for (int r = 1; r < 16; ++r) tmax = fmaxf(tmax, fmaxf(sa[r], sb[r]));
        tmax = fmaxf(tmax, __shfl_xor(tmax, 32));

        if (__any(tmax > m_run + DEFER_THR)) {
            float mnew = fmaxf(m_run, tmax);
            float f = exp2f(m_run - mnew);
            l_run *= f;
            m_run = mnew;
#pragma unroll
            for (int r = 0; r < 16; ++r) o[r] *= f;
        }

        float psum = 0.f;
#pragma unroll
        for (int r = 0; r < 16; ++r) { sa[r] = exp2f(sa[r] - m_run); psum += sa[r]; }
#pragma unroll
        for (int r = 0; r < 16; ++r) { sb[r] = exp2f(sb[r] - m_run); psum += sb[r]; }
        psum += __shfl_xor(psum, 32);
        l_run += psum;

        // ---- P fragments direct from accumulator (V kappa-permuted) ----
        u32x4 pa0, pa1, pb0, pb1;
        pa0.x = pack_bf16x2(sa[0],  sa[1]);  pa0.y = pack_bf16x2(sa[2],  sa[3]);
        pa0.z = pack_bf16x2(sa[4],  sa[5]);  pa0.w = pack_bf16x2(sa[6],  sa[7]);
        pa1.x = pack_bf16x2(sa[8],  sa[9]);  pa1.y = pack_bf16x2(sa[10], sa[11]);
        pa1.z = pack_bf16x2(sa[12], sa[13]); pa1.w = pack_bf16x2(sa[14], sa[15]);
        pb0.x = pack_bf16x2(sb[0],  sb[1]);  pb0.y = pack_bf16x2(sb[2],  sb[3]);
        pb0.z = pack_bf16x2(sb[4],  sb[5]);  pb0.w = pack_bf16x2(sb[6],  sb[7]);
        pb1.x = pack_bf16x2(sb[8],  sb[9]);  pb1.y = pack_bf16x2(sb[10], sb[11]);
        pb1.z = pack_bf16x2(sb[12], sb[13]); pb1.w = pack_bf16x2(sb[14], sb[15]);

        o = __builtin_amdgcn_mfma_f32_32x32x16_bf16(vfA0, __builtin_bit_cast(bf16x8, pa0), o, 0, 0, 0);
        o = __builtin_amdgcn_mfma_f32_32x32x16_bf16(vfA1, __builtin_bit_cast(bf16x8, pa1), o, 0, 0, 0);
        o = __builtin_amdgcn_mfma_f32_32x32x16_bf16(vfB0, __builtin_bit_cast(bf16x8, pb0), o, 0, 0, 0);
        o = __builtin_amdgcn_mfma_f32_32x32x16_bf16(vfB1, __builtin_bit_cast(bf16x8, pb1), o, 0, 0, 0);
    }

    // ---- publish partials ----
#pragma unroll
    for (int r = 0; r < 16; ++r) {
        int d = (r & 3) + 8 * (r >> 2) + 4 * hi;
        o_lds[w][d][col] = o[r];
    }
    if (hi == 0) { m_lds[w][col] = m_run; l_lds[w][col] = l_run; }
    __syncthreads();

    // ---- combine 8 splits -> agg bf16 [B][N][32] ----
    {
        const int qq = tid >> 4;
        const int dp = tid & 15;
        float ms[SPLITS];
        float mstar = -3e38f;
#pragma unroll
        for (int s = 0; s < SPLITS; ++s) { ms[s] = m_lds[s][qq]; mstar = fmaxf(mstar, ms[s]); }
        float wn[SPLITS];
        float den = 0.f;
#pragma unroll
        for (int s = 0; s < SPLITS; ++s) {
            wn[s] = exp2f(ms[s] - mstar);
            den = fmaf(wn[s], l_lds[s][qq], den);
        }
        float inv = 1.f / den;
#pragma unroll
        for (int s = 0; s < SPLITS; ++s) wn[s] *= inv;
        float a0 = 0.f, a1 = 0.f;
#pragma unroll
        for (int s = 0; s < SPLITS; ++s) {
            a0 = fmaf(wn[s], o_lds[s][2 * dp][qq], a0);
            a1 = fmaf(wn[s], o_lds[s][2 * dp + 1][qq], a1);
        }
        u32* dst = reinterpret_cast<u32*>(agg + ((size_t)b * NDIM + q0 + qq) * CLD);
        dst[dp] = pack_bf16x2(a0, a1);
    }
}

// ---------------- Kernel 3: output projection + BN4 + ReLU + residual (vector) ----------------
// grid (N/256, B, 8), block 256 = 4 waves. Wave: 8 outputs x 256 n; thread: 8 o x 4 n.
// agg bf16 [B][N][32] read as ushort4 per (n, 4c)-chunk; x/out float4.
__global__ __launch_bounds__(256) void out_proj(
    const u16* __restrict__ agg, const float* __restrict__ wo,
    const float* __restrict__ b4s, const float* __restrict__ b4b,
    const float* __restrict__ b4m, const float* __restrict__ b4v,
    const float* __restrict__ x, const float* __restrict__ gamma,
    float* __restrict__ out)
{
    const int tid   = threadIdx.x;
    const int lane  = tid & 63;
    const int b     = blockIdx.y;
    const int w     = __builtin_amdgcn_readfirstlane(tid >> 6);
    const int obase = blockIdx.z * 32 + w * 8;          // uniform
    const int n     = blockIdx.x * 256 + lane * 4;

    float4 acc[8];
#pragma unroll
    for (int o = 0; o < 8; ++o) acc[o] = make_float4(0.f, 0.f, 0.f, 0.f);

    const float* wbase = wo + (size_t)obase * CLD;      // uniform
    const u16* ab = agg + (size_t)(b * NDIM + n) * CLD;

#pragma unroll 2
    for (int c = 0; c < CLD; c += 4) {
        float4 wq[8];
#pragma unroll
        for (int o = 0; o < 8; ++o)
            wq[o] = *reinterpret_cast<const float4*>(wbase + o * CLD + c);   // s_load
        ushort4 av[4];
#pragma unroll
        for (int j = 0; j < 4; ++j)
            av[j] = *reinterpret_cast<const ushort4*>(ab + j * CLD + c);
#pragma unroll
        for (int cc = 0; cc < 4; ++cc) {
            float a0 = bfbits2f((cc == 0) ? av[0].x : (cc == 1) ? av[0].y : (cc == 2) ? av[0].z : av[0].w);
            float a1 = bfbits2f((cc == 0) ? av[1].x : (cc == 1) ? av[1].y : (cc == 2) ? av[1].z : av[1].w);
            float a2 = bfbits2f((cc == 0) ? av[2].x : (cc == 1) ? av[2].y : (cc == 2) ? av[2].z : av[2].w);
            float a3 = bfbits2f((cc == 0) ? av[3].x : (cc == 1) ? av[3].y : (cc == 2) ? av[3].z : av[3].w);
#pragma unroll
            for (int o = 0; o < 8; ++o) {
                float wv = (cc == 0) ? wq[o].x : (cc == 1) ? wq[o].y : (cc == 2) ? wq[o].z : wq[o].w;
                acc[o].x = fmaf(wv, a0, acc[o].x);
                acc[o].y = fmaf(wv, a1, acc[o].y);
                acc[o].z = fmaf(wv, a2, acc[o].z);
                acc[o].w = fmaf(wv, a3, acc[o].w);
            }
        }
    }

    const float gm = gamma[0];
#pragma unroll
    for (int o = 0; o < 8; ++o) {
        int oo = obase + o;
        float inv = b4s[oo] / sqrtf(b4v[oo] + EPSBN);
        float bi  = b4b[oo] - b4m[oo] * inv;
        const size_t idx = ((size_t)b * CDIM + oo) * NDIM + n;
        float4 xv = *reinterpret_cast<const float4*>(x + idx);
        float4 r;
        r.x = fmaf(gm, fmaxf(fmaf(acc[o].x, inv, bi), 0.f), xv.x);
        r.y = fmaf(gm, fmaxf(fmaf(acc[o].y, inv, bi), 0.f), xv.y);
        r.z = fmaf(gm, fmaxf(fmaf(acc[o].z, inv, bi), 0.f), xv.z);
        r.w = fmaf(gm, fmaxf(fmaf(acc[o].w, inv, bi), 0.f), xv.w);
        *reinterpret_cast<float4*>(out + idx) = r;
    }
}

extern "C" void kernel_launch(void* const* d_in, const int* in_sizes, int n_in,
                              void* d_out, int out_size, void* d_ws, size_t ws_size,
                              hipStream_t stream) {
    const float* x   = (const float*)d_in[0];
    const float* w1  = (const float*)d_in[1];
    const float* w2  = (const float*)d_in[2];
    const float* w3  = (const float*)d_in[3];
    const float* wo  = (const float*)d_in[4];
    const float* b1s = (const float*)d_in[5];
    const float* b1b = (const float*)d_in[6];
    const float* b1m = (const float*)d_in[7];
    const float* b1v = (const float*)d_in[8];
    const float* b2s = (const float*)d_in[9];
    const float* b2b = (const float*)d_in[10];
    const float* b2m = (const float*)d_in[11];
    const float* b2v = (const float*)d_in[12];
    const float* b3s = (const float*)d_in[13];
    const float* b3b = (const float*)d_in[14];
    const float* b3m = (const float*)d_in[15];
    const float* b3v = (const float*)d_in[16];
    const float* b4s = (const float*)d_in[17];
    const float* b4b = (const float*)d_in[18];
    const float* b4m = (const float*)d_in[19];
    const float* b4v = (const float*)d_in[20];
    const float* gm  = (const float*)d_in[21];
    float* out = (float*)d_out;

    // ws layout (bytes):
    //   [0, 1MB)   : qbf bf16 [B][N][32]  (pre-scaled by log2e)
    //   [1MB, 2MB) : kbf bf16 [B][N][32]
    //   [2MB, 3MB) : vbf bf16 [B][N/32][32d][32slot]  (kappa slot order)
    //   [3MB, 4MB) : agg bf16 [B][N][32]
    char* W = (char*)d_ws;
    u16* qbf = (u16*)W;
    u16* kbf = (u16*)(W + (1u << 20));
    u16* vbf = (u16*)(W + (2u << 20));
    u16* agg = (u16*)(W + (3u << 20));

    dim3 gp(NDIM / 64, BATCH, 3);
    proj_qkv<<<gp, 256, 0, stream>>>(x, w1, w2, w3,
                                     b1s, b1b, b1m, b1v,
                                     b2s, b2b, b2m, b2v,
                                     b3s, b3b, b3m, b3v,
                                     qbf, kbf, vbf);

    dim3 ga(NDIM / 32, BATCH);
    attn_mfma<<<ga, 512, 0, stream>>>(qbf, kbf, vbf, agg);

    dim3 go(NDIM / 256, BATCH, 8);
    out_proj<<<go, 256, 0, stream>>>(agg, wo, b4s, b4b, b4m, b4v, x, gm, out);
}

// Round 8
// 70.156 us; speedup vs baseline: 1.1835x; 1.1835x over previous
//
#include <hip/hip_runtime.h>
#include <hip/hip_bf16.h>
#include <math.h>

#define BATCH 4
#define CDIM 256
#define NDIM 4096
#define CLD 32
#define EPSBN 1e-5f
#define SPLITS 8
#define KEYS_PER_WAVE (NDIM / SPLITS)   // 512
#define LOG2E 1.4426950408889634f
#define DEFER_THR 8.0f
#define NT (NDIM / 32)                  // 128 key-tiles per batch

typedef unsigned short u16;
typedef unsigned int u32;
typedef __attribute__((ext_vector_type(8))) short bf16x8;   // 8 bf16 = 4 VGPR MFMA operand
typedef __attribute__((ext_vector_type(16))) float f32x16;  // 32x32 MFMA accumulator
typedef __attribute__((ext_vector_type(4))) u32 u32x4;

__device__ inline u16 f2bf(float x) {
    return __builtin_bit_cast(u16, __float2bfloat16(x));
}
__device__ inline u32 pack_bf16x2(float a, float b) {
    return (u32)f2bf(a) | ((u32)f2bf(b) << 16);
}

// ---------------- Kernel 1: QKV projection + BN + ReLU -> bf16 ----------------
// Round-3/4 proven structure: grid (N/128, B, 3), block 256 = 4 waves. Wave
// g = z*4+w owns 8 channels of one of {w1,w2,w3} x 128 n (2 n/lane, float2 x).
// q (scaled by log2e), k -> [B][N][32] bf16.
// v -> tiled [B][N/32][32d][32slot] bf16, slot = kappa(key&31)
// (kappa: p^=12 if ((p>>2)&3) in {1,2}; preserves even pairs) so attention's
// PV A-operand loads are contiguous and P needs no shuffles.
__global__ __launch_bounds__(256) void proj_qkv(
    const float* __restrict__ x,
    const float* __restrict__ w1, const float* __restrict__ w2, const float* __restrict__ w3,
    const float* __restrict__ b1s, const float* __restrict__ b1b, const float* __restrict__ b1m, const float* __restrict__ b1v,
    const float* __restrict__ b2s, const float* __restrict__ b2b, const float* __restrict__ b2m, const float* __restrict__ b2v,
    const float* __restrict__ b3s, const float* __restrict__ b3b, const float* __restrict__ b3m, const float* __restrict__ b3v,
    u16* __restrict__ qo, u16* __restrict__ ko, u16* __restrict__ vo)
{
    const int tid  = threadIdx.x;
    const int lane = tid & 63;
    const int b    = blockIdx.y;
    const int g    = __builtin_amdgcn_readfirstlane(blockIdx.z * 4 + (tid >> 6)); // 0..11 uniform
    const int mat  = g >> 2;             // 0:q/w1 1:k/w2 2:v/w3
    const int ch0  = (g & 3) * 8;
    const int n    = blockIdx.x * 128 + lane * 2;

    const float* wb = ((mat == 0) ? w1 : (mat == 1) ? w2 : w3) + (size_t)ch0 * CDIM;

    float2 acc[8];
#pragma unroll
    for (int o = 0; o < 8; ++o) acc[o] = make_float2(0.f, 0.f);

    const float* xb = x + (size_t)b * CDIM * NDIM + n;

#pragma unroll 2
    for (int c = 0; c < CDIM; c += 4) {
        float4 wq[8];
#pragma unroll
        for (int o = 0; o < 8; ++o)
            wq[o] = *reinterpret_cast<const float4*>(wb + o * CDIM + c);  // uniform -> s_load
        float2 xv[4];
#pragma unroll
        for (int cc = 0; cc < 4; ++cc)
            xv[cc] = *reinterpret_cast<const float2*>(xb + (size_t)(c + cc) * NDIM);
#pragma unroll
        for (int cc = 0; cc < 4; ++cc) {
#pragma unroll
            for (int o = 0; o < 8; ++o) {
                float wv = (cc == 0) ? wq[o].x : (cc == 1) ? wq[o].y : (cc == 2) ? wq[o].z : wq[o].w;
                acc[o].x = fmaf(wv, xv[cc].x, acc[o].x);
                acc[o].y = fmaf(wv, xv[cc].y, acc[o].y);
            }
        }
    }

    const float* ps = (mat == 0) ? b1s : (mat == 1) ? b2s : b3s;
    const float* pb = (mat == 0) ? b1b : (mat == 1) ? b2b : b3b;
    const float* pm = (mat == 0) ? b1m : (mat == 1) ? b2m : b3m;
    const float* pv = (mat == 0) ? b1v : (mat == 1) ? b2v : b3v;
    const float qscale = (mat == 0) ? LOG2E : 1.0f;

    float y0[8], y1[8];
#pragma unroll
    for (int o = 0; o < 8; ++o) {
        float inv = ps[ch0 + o] / sqrtf(pv[ch0 + o] + EPSBN);
        float mb  = pm[ch0 + o];
        float bb  = pb[ch0 + o];
        y0[o] = fmaxf((acc[o].x - mb) * inv + bb, 0.f) * qscale;
        y1[o] = fmaxf((acc[o].y - mb) * inv + bb, 0.f) * qscale;
    }

    if (mat < 2) {
        u16* dst = ((mat == 0) ? qo : ko) + ((size_t)b * NDIM + n) * CLD + ch0;
        u32x4 s0, s1;
        s0.x = pack_bf16x2(y0[0], y0[1]); s0.y = pack_bf16x2(y0[2], y0[3]);
        s0.z = pack_bf16x2(y0[4], y0[5]); s0.w = pack_bf16x2(y0[6], y0[7]);
        s1.x = pack_bf16x2(y1[0], y1[1]); s1.y = pack_bf16x2(y1[2], y1[3]);
        s1.z = pack_bf16x2(y1[4], y1[5]); s1.w = pack_bf16x2(y1[6], y1[7]);
        *reinterpret_cast<u32x4*>(dst)       = s0;
        *reinterpret_cast<u32x4*>(dst + CLD) = s1;
    } else {
        // tiled + kappa slot; n even -> pair (p, p+1) moves intact
        int t = n >> 5;
        int p = n & 31;
        int q2 = (p >> 2) & 3;
        if (q2 == 1 || q2 == 2) p ^= 12;
        u16* base = vo + (size_t)(b * NT + t) * 1024 + p;
#pragma unroll
        for (int o = 0; o < 8; ++o)
            *reinterpret_cast<u32*>(base + (ch0 + o) * 32) = pack_bf16x2(y0[o], y1[o]);
    }
}

// ---------------- Kernel 2: MFMA flash attention, 8-way split-in-block ----------------
// grid (N/32, B), block 512 = 8 waves; all waves share one 32-query tile, each
// owns 512 keys. Scores in log2 domain (q pre-scaled by log2e). V tiled +
// kappa-permuted: P fragments come directly from accumulator registers and V
// loads are contiguous. Defer-max THR=8 skips identity O-rescales.
// LDS combine writes agg f32 [B][32][N] (coalesced along n).
__global__ __launch_bounds__(512, 4) void attn_mfma(
    const u16* __restrict__ q, const u16* __restrict__ k, const u16* __restrict__ v,
    float* __restrict__ agg)
{
    __shared__ float o_lds[SPLITS][32][32];   // 32 KB
    __shared__ float m_lds[SPLITS][32];
    __shared__ float l_lds[SPLITS][32];

    const int tid  = threadIdx.x;
    const int lane = tid & 63;
    const int w    = tid >> 6;            // split 0..7
    const int b    = blockIdx.y;
    const int q0   = blockIdx.x * 32;
    const int col  = lane & 31;
    const int hi   = lane >> 5;

    const u16* qp = q + ((size_t)b * NDIM + q0 + col) * CLD + 8 * hi;
    bf16x8 qf0 = *reinterpret_cast<const bf16x8*>(qp);
    bf16x8 qf1 = *reinterpret_cast<const bf16x8*>(qp + 16);

    f32x16 o = {0.f,0.f,0.f,0.f, 0.f,0.f,0.f,0.f, 0.f,0.f,0.f,0.f, 0.f,0.f,0.f,0.f};
    float m_run = -3e38f, l_run = 0.f;

    const int kstart = w * KEYS_PER_WAVE;
    const u16* kb = k + (size_t)b * NDIM * CLD;
    const u16* vb = v + (size_t)(b * NT) * 1024 + (size_t)col * 32 + 8 * hi;

    for (int kt = 0; kt < KEYS_PER_WAVE; kt += 64) {
        const int k0 = kstart + kt;
        // ---- loads for two 32-key tiles (issued together) ----
        const u16* kpA = kb + (size_t)(k0 + col) * CLD + 8 * hi;
        bf16x8 kfA0 = *reinterpret_cast<const bf16x8*>(kpA);
        bf16x8 kfA1 = *reinterpret_cast<const bf16x8*>(kpA + 16);
        const u16* kpB = kpA + 32 * CLD;
        bf16x8 kfB0 = *reinterpret_cast<const bf16x8*>(kpB);
        bf16x8 kfB1 = *reinterpret_cast<const bf16x8*>(kpB + 16);

        const u16* vp = vb + (size_t)(k0 >> 5) * 1024;
        bf16x8 vfA0 = *reinterpret_cast<const bf16x8*>(vp);
        bf16x8 vfA1 = *reinterpret_cast<const bf16x8*>(vp + 16);
        bf16x8 vfB0 = *reinterpret_cast<const bf16x8*>(vp + 1024);
        bf16x8 vfB1 = *reinterpret_cast<const bf16x8*>(vp + 1040);

        f32x16 sa = {0.f,0.f,0.f,0.f, 0.f,0.f,0.f,0.f, 0.f,0.f,0.f,0.f, 0.f,0.f,0.f,0.f};
        f32x16 sb = {0.f,0.f,0.f,0.f, 0.f,0.f,0.f,0.f, 0.f,0.f,0.f,0.f, 0.f,0.f,0.f,0.f};
        sa = __builtin_amdgcn_mfma_f32_32x32x16_bf16(kfA0, qf0, sa, 0, 0, 0);
        sa = __builtin_amdgcn_mfma_f32_32x32x16_bf16(kfA1, qf1, sa, 0, 0, 0);
        sb = __builtin_amdgcn_mfma_f32_32x32x16_bf16(kfB0, qf0, sb, 0, 0, 0);
        sb = __builtin_amdgcn_mfma_f32_32x32x16_bf16(kfB1, qf1, sb, 0, 0, 0);

        // ---- online softmax over 64 keys (log2 domain, defer-max THR=8) ----
        float tmax = fmaxf(sa[0], sb[0]);
#pragma unroll
        for (int r = 1; r < 16; ++r) tmax = fmaxf(tmax, fmaxf(sa[r], sb[r]));
        tmax = fmaxf(tmax, __shfl_xor(tmax, 32));

        if (__any(tmax > m_run + DEFER_THR)) {
            float mnew = fmaxf(m_run, tmax);
            float f = exp2f(m_run - mnew);
            l_run *= f;
            m_run = mnew;
#pragma unroll
            for (int r = 0; r < 16; ++r) o[r] *= f;
        }

        float psum = 0.f;
#pragma unroll
        for (int r = 0; r < 16; ++r) { sa[r] = exp2f(sa[r] - m_run); psum += sa[r]; }
#pragma unroll
        for (int r = 0; r < 16; ++r) { sb[r] = exp2f(sb[r] - m_run); psum += sb[r]; }
        psum += __shfl_xor(psum, 32);
        l_run += psum;

        // ---- P fragments direct from accumulator (V kappa-permuted) ----
        u32x4 pa0, pa1, pb0, pb1;
        pa0.x = pack_bf16x2(sa[0],  sa[1]);  pa0.y = pack_bf16x2(sa[2],  sa[3]);
        pa0.z = pack_bf16x2(sa[4],  sa[5]);  pa0.w = pack_bf16x2(sa[6],  sa[7]);
        pa1.x = pack_bf16x2(sa[8],  sa[9]);  pa1.y = pack_bf16x2(sa[10], sa[11]);
        pa1.z = pack_bf16x2(sa[12], sa[13]); pa1.w = pack_bf16x2(sa[14], sa[15]);
        pb0.x = pack_bf16x2(sb[0],  sb[1]);  pb0.y = pack_bf16x2(sb[2],  sb[3]);
        pb0.z = pack_bf16x2(sb[4],  sb[5]);  pb0.w = pack_bf16x2(sb[6],  sb[7]);
        pb1.x = pack_bf16x2(sb[8],  sb[9]);  pb1.y = pack_bf16x2(sb[10], sb[11]);
        pb1.z = pack_bf16x2(sb[12], sb[13]); pb1.w = pack_bf16x2(sb[14], sb[15]);

        o = __builtin_amdgcn_mfma_f32_32x32x16_bf16(vfA0, __builtin_bit_cast(bf16x8, pa0), o, 0, 0, 0);
        o = __builtin_amdgcn_mfma_f32_32x32x16_bf16(vfA1, __builtin_bit_cast(bf16x8, pa1), o, 0, 0, 0);
        o = __builtin_amdgcn_mfma_f32_32x32x16_bf16(vfB0, __builtin_bit_cast(bf16x8, pb0), o, 0, 0, 0);
        o = __builtin_amdgcn_mfma_f32_32x32x16_bf16(vfB1, __builtin_bit_cast(bf16x8, pb1), o, 0, 0, 0);
    }

    // ---- publish partials ----
#pragma unroll
    for (int r = 0; r < 16; ++r) {
        int d = (r & 3) + 8 * (r >> 2) + 4 * hi;
        o_lds[w][d][col] = o[r];
    }
    if (hi == 0) { m_lds[w][col] = m_run; l_lds[w][col] = l_run; }
    __syncthreads();

    // ---- combine 8 splits -> agg f32 [B][32][N] (coalesced dword along n) ----
    {
        const int qq = tid & 31;
        const int d0 = tid >> 5;          // 0..15
        float ms[SPLITS];
        float mstar = -3e38f;
#pragma unroll
        for (int s = 0; s < SPLITS; ++s) { ms[s] = m_lds[s][qq]; mstar = fmaxf(mstar, ms[s]); }
        float wn[SPLITS];
        float den = 0.f;
#pragma unroll
        for (int s = 0; s < SPLITS; ++s) {
            wn[s] = exp2f(ms[s] - mstar);
            den = fmaf(wn[s], l_lds[s][qq], den);
        }
        float inv = 1.f / den;
#pragma unroll
        for (int s = 0; s < SPLITS; ++s) wn[s] *= inv;
#pragma unroll
        for (int dd = 0; dd < 2; ++dd) {
            int d = d0 + 16 * dd;
            float a2 = 0.f;
#pragma unroll
            for (int s = 0; s < SPLITS; ++s) a2 = fmaf(wn[s], o_lds[s][d][qq], a2);
            agg[((size_t)b * CLD + d) * NDIM + q0 + qq] = a2;
        }
    }
}

// ---------------- Kernel 3: output projection + BN4 + ReLU + residual ----------------
// Round-3-proposal proven structure: grid (N/256, B, 8), block 256 = 4 waves.
// Wave: 8 outputs x 256 n; thread: 8 o x 4 n. agg f32 [B][32][N] float4 loads.
__global__ __launch_bounds__(256) void out_proj(
    const float* __restrict__ agg, const float* __restrict__ wo,
    const float* __restrict__ b4s, const float* __restrict__ b4b,
    const float* __restrict__ b4m, const float* __restrict__ b4v,
    const float* __restrict__ x, const float* __restrict__ gamma,
    float* __restrict__ out)
{
    const int tid   = threadIdx.x;
    const int lane  = tid & 63;
    const int b     = blockIdx.y;
    const int w     = __builtin_amdgcn_readfirstlane(tid >> 6);
    const int obase = blockIdx.z * 32 + w * 8;          // uniform
    const int n     = blockIdx.x * 256 + lane * 4;

    float4 acc[8];
#pragma unroll
    for (int o = 0; o < 8; ++o) acc[o] = make_float4(0.f, 0.f, 0.f, 0.f);

    const float* wbase = wo + (size_t)obase * CLD;      // uniform

#pragma unroll 2
    for (int c = 0; c < CLD; c += 4) {
        float4 wq[8];
#pragma unroll
        for (int o = 0; o < 8; ++o)
            wq[o] = *reinterpret_cast<const float4*>(wbase + o * CLD + c);   // s_load
        float4 av[4];
#pragma unroll
        for (int cc = 0; cc < 4; ++cc)
            av[cc] = *reinterpret_cast<const float4*>(agg + ((size_t)b * CLD + c + cc) * NDIM + n);
#pragma unroll
        for (int cc = 0; cc < 4; ++cc) {
#pragma unroll
            for (int o = 0; o < 8; ++o) {
                float wv = (cc == 0) ? wq[o].x : (cc == 1) ? wq[o].y : (cc == 2) ? wq[o].z : wq[o].w;
                acc[o].x = fmaf(wv, av[cc].x, acc[o].x);
                acc[o].y = fmaf(wv, av[cc].y, acc[o].y);
                acc[o].z = fmaf(wv, av[cc].z, acc[o].z);
                acc[o].w = fmaf(wv, av[cc].w, acc[o].w);
            }
        }
    }

    const float gm = gamma[0];
#pragma unroll
    for (int o = 0; o < 8; ++o) {
        int oo = obase + o;
        float inv = b4s[oo] / sqrtf(b4v[oo] + EPSBN);
        float bi  = b4b[oo] - b4m[oo] * inv;
        const size_t idx = ((size_t)b * CDIM + oo) * NDIM + n;
        float4 xv = *reinterpret_cast<const float4*>(x + idx);
        float4 r;
        r.x = fmaf(gm, fmaxf(fmaf(acc[o].x, inv, bi), 0.f), xv.x);
        r.y = fmaf(gm, fmaxf(fmaf(acc[o].y, inv, bi), 0.f), xv.y);
        r.z = fmaf(gm, fmaxf(fmaf(acc[o].z, inv, bi), 0.f), xv.z);
        r.w = fmaf(gm, fmaxf(fmaf(acc[o].w, inv, bi), 0.f), xv.w);
        *reinterpret_cast<float4*>(out + idx) = r;
    }
}

extern "C" void kernel_launch(void* const* d_in, const int* in_sizes, int n_in,
                              void* d_out, int out_size, void* d_ws, size_t ws_size,
                              hipStream_t stream) {
    const float* x   = (const float*)d_in[0];
    const float* w1  = (const float*)d_in[1];
    const float* w2  = (const float*)d_in[2];
    const float* w3  = (const float*)d_in[3];
    const float* wo  = (const float*)d_in[4];
    const float* b1s = (const float*)d_in[5];
    const float* b1b = (const float*)d_in[6];
    const float* b1m = (const float*)d_in[7];
    const float* b1v = (const float*)d_in[8];
    const float* b2s = (const float*)d_in[9];
    const float* b2b = (const float*)d_in[10];
    const float* b2m = (const float*)d_in[11];
    const float* b2v = (const float*)d_in[12];
    const float* b3s = (const float*)d_in[13];
    const float* b3b = (const float*)d_in[14];
    const float* b3m = (const float*)d_in[15];
    const float* b3v = (const float*)d_in[16];
    const float* b4s = (const float*)d_in[17];
    const float* b4b = (const float*)d_in[18];
    const float* b4m = (const float*)d_in[19];
    const float* b4v = (const float*)d_in[20];
    const float* gm  = (const float*)d_in[21];
    float* out = (float*)d_out;

    // ws layout (bytes):
    //   [0, 1MB)   : qbf bf16 [B][N][32]  (pre-scaled by log2e)
    //   [1MB, 2MB) : kbf bf16 [B][N][32]
    //   [2MB, 3MB) : vbf bf16 [B][N/32][32d][32slot]  (kappa slot order)
    //   [3MB, 5MB) : agg f32  [B][32][N]
    char* W = (char*)d_ws;
    u16* qbf = (u16*)W;
    u16* kbf = (u16*)(W + (1u << 20));
    u16* vbf = (u16*)(W + (2u << 20));
    float* agg = (float*)(W + (3u << 20));

    dim3 gp(NDIM / 128, BATCH, 3);
    proj_qkv<<<gp, 256, 0, stream>>>(x, w1, w2, w3,
                                     b1s, b1b, b1m, b1v,
                                     b2s, b2b, b2m, b2v,
                                     b3s, b3b, b3m, b3v,
                                     qbf, kbf, vbf);

    dim3 ga(NDIM / 32, BATCH);
    attn_mfma<<<ga, 512, 0, stream>>>(qbf, kbf, vbf, agg);

    dim3 go(NDIM / 256, BATCH, 8);
    out_proj<<<go, 256, 0, stream>>>(agg, wo, b4s, b4b, b4m, b4v, x, gm, out);
}

// Round 9
// 55.155 us; speedup vs baseline: 1.5054x; 1.2720x over previous
//
#include <hip/hip_runtime.h>
#include <hip/hip_bf16.h>
#include <math.h>

#define BATCH 4
#define CDIM 256
#define NDIM 4096
#define CLD 32
#define EPSBN 1e-5f
#define SPLITS 8
#define KEYS_PER_WAVE (NDIM / SPLITS)   // 512
#define LOG2E 1.4426950408889634f
#define DEFER_THR 8.0f
#define NT (NDIM / 32)                  // 128 key-tiles per batch

typedef unsigned short u16;
typedef unsigned int u32;
typedef __attribute__((ext_vector_type(8))) short bf16x8;   // 8 bf16 = 4 VGPR MFMA operand
typedef __attribute__((ext_vector_type(16))) float f32x16;  // 32x32 MFMA accumulator
typedef __attribute__((ext_vector_type(4))) u32 u32x4;
typedef __attribute__((ext_vector_type(2))) u32 u32x2;

__device__ inline u16 f2bf(float x) {
    return __builtin_bit_cast(u16, __float2bfloat16(x));
}
__device__ inline u32 pack_bf16x2(float a, float b) {
    return (u32)f2bf(a) | ((u32)f2bf(b) << 16);
}
__device__ inline bf16x8 pack8(float4 a, float4 b) {
    u32x4 u;
    u.x = pack_bf16x2(a.x, a.y); u.y = pack_bf16x2(a.z, a.w);
    u.z = pack_bf16x2(b.x, b.y); u.w = pack_bf16x2(b.z, b.w);
    return __builtin_bit_cast(bf16x8, u);
}

// ---------------- Kernel 1: MFMA QKV projection + BN + ReLU -> bf16 ----------------
// grid (32, 3, B), block 256 = 4 waves. Wave w: output tile = mat (blockIdx.y)
// x 32 n (tile tl = blockIdx.x*4+w), K = 256 -> 16 MFMA of 32x32x16.
// A-frag: W_m[o=col][c=16f+8hi+i] (32B contiguous f32, cvt->bf16; 16 frags held).
// B-frag: x[c][n0+col] via 8 coalesced dword loads per frag.
// D[col=n][row=o=(r&3)+8(r>>2)+4hi] (verified m74/m101 layout).
// q (xLOG2E folded into BN), k -> [B][N][32]; v -> tiled [B][NT][32d][32slot],
// slot = kappa(key&31) (kappa: p^=12 if ((p>>2)&3) in {1,2}).
__global__ __launch_bounds__(256) void proj_qkv(
    const float* __restrict__ x,
    const float* __restrict__ w1, const float* __restrict__ w2, const float* __restrict__ w3,
    const float* __restrict__ b1s, const float* __restrict__ b1b, const float* __restrict__ b1m, const float* __restrict__ b1v,
    const float* __restrict__ b2s, const float* __restrict__ b2b, const float* __restrict__ b2m, const float* __restrict__ b2v,
    const float* __restrict__ b3s, const float* __restrict__ b3b, const float* __restrict__ b3m, const float* __restrict__ b3v,
    u16* __restrict__ qo, u16* __restrict__ ko, u16* __restrict__ vo)
{
    __shared__ float2 sbn[32];          // (inv, bias) for this mat's 32 channels

    const int tid  = threadIdx.x;
    const int lane = tid & 63;
    const int col  = lane & 31;
    const int hi   = lane >> 5;
    const int wv   = tid >> 6;
    const int mat  = blockIdx.y;        // 0:q/w1 1:k/w2 2:v/w3
    const int b    = blockIdx.z;
    const int tl   = blockIdx.x * 4 + wv;   // n-tile within batch, 0..127
    const int n0   = tl * 32;

    if (tid < 32) {
        const float* ps = (mat == 0) ? b1s : (mat == 1) ? b2s : b3s;
        const float* pb = (mat == 0) ? b1b : (mat == 1) ? b2b : b3b;
        const float* pm = (mat == 0) ? b1m : (mat == 1) ? b2m : b3m;
        const float* pv = (mat == 0) ? b1v : (mat == 1) ? b2v : b3v;
        float inv  = ps[tid] / sqrtf(pv[tid] + EPSBN);
        float bias = pb[tid] - pm[tid] * inv;
        if (mat == 0) { inv *= LOG2E; bias *= LOG2E; }   // relu(y)*s == relu(y*s), s>0
        sbn[tid] = make_float2(inv, bias);
    }
    __syncthreads();

    // A-frags: W_m[o=col][c], 16 frags of k=16, held in VGPRs
    const float* wb = ((mat == 0) ? w1 : (mat == 1) ? w2 : w3) + (size_t)col * CDIM + 8 * hi;
    bf16x8 wf[16];
#pragma unroll
    for (int f = 0; f < 16; ++f) {
        float4 a = *reinterpret_cast<const float4*>(wb + 16 * f);
        float4 c = *reinterpret_cast<const float4*>(wb + 16 * f + 4);
        wf[f] = pack8(a, c);
    }

    const float* xb = x + (size_t)b * CDIM * NDIM + n0 + col;

    f32x16 acc = {0.f,0.f,0.f,0.f, 0.f,0.f,0.f,0.f, 0.f,0.f,0.f,0.f, 0.f,0.f,0.f,0.f};
#pragma unroll
    for (int f = 0; f < 16; ++f) {
        float xv[8];
#pragma unroll
        for (int i = 0; i < 8; ++i)
            xv[i] = xb[(size_t)(16 * f + 8 * hi + i) * NDIM];   // coalesced along n
        u32x4 u;
        u.x = pack_bf16x2(xv[0], xv[1]); u.y = pack_bf16x2(xv[2], xv[3]);
        u.z = pack_bf16x2(xv[4], xv[5]); u.w = pack_bf16x2(xv[6], xv[7]);
        acc = __builtin_amdgcn_mfma_f32_32x32x16_bf16(wf[f], __builtin_bit_cast(bf16x8, u), acc, 0, 0, 0);
    }

    if (mat < 2) {
        // [B][N][32]: lane owns n=n0+col; o chunks {0-3,8-11,16-19,24-27}+4hi
        u16* dst = ((mat == 0) ? qo : ko) + ((size_t)b * NDIM + n0 + col) * CLD;
#pragma unroll
        for (int g2 = 0; g2 < 4; ++g2) {
            float y[4];
#pragma unroll
            for (int j = 0; j < 4; ++j) {
                int o = 8 * g2 + 4 * hi + j;
                float2 ib = sbn[o];
                y[j] = fmaxf(fmaf(acc[4 * g2 + j], ib.x, ib.y), 0.f);
            }
            u32x2 s;
            s.x = pack_bf16x2(y[0], y[1]); s.y = pack_bf16x2(y[2], y[3]);
            *reinterpret_cast<u32x2*>(dst + 8 * g2 + 4 * hi) = s;
        }
    } else {
        // tiled V: [B][NT][32d][32slot], slot = kappa(col), rows = d
        int p = col;
        int q2 = (p >> 2) & 3;
        if (q2 == 1 || q2 == 2) p ^= 12;
        u16* base = vo + (size_t)(b * NT + tl) * 1024 + p;
#pragma unroll
        for (int r = 0; r < 16; ++r) {
            int d = (r & 3) + 8 * (r >> 2) + 4 * hi;
            float2 ib = sbn[d];
            base[d * 32] = f2bf(fmaxf(fmaf(acc[r], ib.x, ib.y), 0.f));
        }
    }
}

// ---------------- Kernel 2: MFMA flash attention, 8-way split-in-block ----------------
// (byte-identical to round 8)
__global__ __launch_bounds__(512, 4) void attn_mfma(
    const u16* __restrict__ q, const u16* __restrict__ k, const u16* __restrict__ v,
    float* __restrict__ agg)
{
    __shared__ float o_lds[SPLITS][32][32];   // 32 KB
    __shared__ float m_lds[SPLITS][32];
    __shared__ float l_lds[SPLITS][32];

    const int tid  = threadIdx.x;
    const int lane = tid & 63;
    const int w    = tid >> 6;            // split 0..7
    const int b    = blockIdx.y;
    const int q0   = blockIdx.x * 32;
    const int col  = lane & 31;
    const int hi   = lane >> 5;

    const u16* qp = q + ((size_t)b * NDIM + q0 + col) * CLD + 8 * hi;
    bf16x8 qf0 = *reinterpret_cast<const bf16x8*>(qp);
    bf16x8 qf1 = *reinterpret_cast<const bf16x8*>(qp + 16);

    f32x16 o = {0.f,0.f,0.f,0.f, 0.f,0.f,0.f,0.f, 0.f,0.f,0.f,0.f, 0.f,0.f,0.f,0.f};
    float m_run = -3e38f, l_run = 0.f;

    const int kstart = w * KEYS_PER_WAVE;
    const u16* kb = k + (size_t)b * NDIM * CLD;
    const u16* vb = v + (size_t)(b * NT) * 1024 + (size_t)col * 32 + 8 * hi;

    for (int kt = 0; kt < KEYS_PER_WAVE; kt += 64) {
        const int k0 = kstart + kt;
        const u16* kpA = kb + (size_t)(k0 + col) * CLD + 8 * hi;
        bf16x8 kfA0 = *reinterpret_cast<const bf16x8*>(kpA);
        bf16x8 kfA1 = *reinterpret_cast<const bf16x8*>(kpA + 16);
        const u16* kpB = kpA + 32 * CLD;
        bf16x8 kfB0 = *reinterpret_cast<const bf16x8*>(kpB);
        bf16x8 kfB1 = *reinterpret_cast<const bf16x8*>(kpB + 16);

        const u16* vp = vb + (size_t)(k0 >> 5) * 1024;
        bf16x8 vfA0 = *reinterpret_cast<const bf16x8*>(vp);
        bf16x8 vfA1 = *reinterpret_cast<const bf16x8*>(vp + 16);
        bf16x8 vfB0 = *reinterpret_cast<const bf16x8*>(vp + 1024);
        bf16x8 vfB1 = *reinterpret_cast<const bf16x8*>(vp + 1040);

        f32x16 sa = {0.f,0.f,0.f,0.f, 0.f,0.f,0.f,0.f, 0.f,0.f,0.f,0.f, 0.f,0.f,0.f,0.f};
        f32x16 sb = {0.f,0.f,0.f,0.f, 0.f,0.f,0.f,0.f, 0.f,0.f,0.f,0.f, 0.f,0.f,0.f,0.f};
        sa = __builtin_amdgcn_mfma_f32_32x32x16_bf16(kfA0, qf0, sa, 0, 0, 0);
        sa = __builtin_amdgcn_mfma_f32_32x32x16_bf16(kfA1, qf1, sa, 0, 0, 0);
        sb = __builtin_amdgcn_mfma_f32_32x32x16_bf16(kfB0, qf0, sb, 0, 0, 0);
        sb = __builtin_amdgcn_mfma_f32_32x32x16_bf16(kfB1, qf1, sb, 0, 0, 0);

        float tmax = fmaxf(sa[0], sb[0]);
#pragma unroll
        for (int r = 1; r < 16; ++r) tmax = fmaxf(tmax, fmaxf(sa[r], sb[r]));
        tmax = fmaxf(tmax, __shfl_xor(tmax, 32));

        if (__any(tmax > m_run + DEFER_THR)) {
            float mnew = fmaxf(m_run, tmax);
            float f = exp2f(m_run - mnew);
            l_run *= f;
            m_run = mnew;
#pragma unroll
            for (int r = 0; r < 16; ++r) o[r] *= f;
        }

        float psum = 0.f;
#pragma unroll
        for (int r = 0; r < 16; ++r) { sa[r] = exp2f(sa[r] - m_run); psum += sa[r]; }
#pragma unroll
        for (int r = 0; r < 16; ++r) { sb[r] = exp2f(sb[r] - m_run); psum += sb[r]; }
        psum += __shfl_xor(psum, 32);
        l_run += psum;

        u32x4 pa0, pa1, pb0, pb1;
        pa0.x = pack_bf16x2(sa[0],  sa[1]);  pa0.y = pack_bf16x2(sa[2],  sa[3]);
        pa0.z = pack_bf16x2(sa[4],  sa[5]);  pa0.w = pack_bf16x2(sa[6],  sa[7]);
        pa1.x = pack_bf16x2(sa[8],  sa[9]);  pa1.y = pack_bf16x2(sa[10], sa[11]);
        pa1.z = pack_bf16x2(sa[12], sa[13]); pa1.w = pack_bf16x2(sa[14], sa[15]);
        pb0.x = pack_bf16x2(sb[0],  sb[1]);  pb0.y = pack_bf16x2(sb[2],  sb[3]);
        pb0.z = pack_bf16x2(sb[4],  sb[5]);  pb0.w = pack_bf16x2(sb[6],  sb[7]);
        pb1.x = pack_bf16x2(sb[8],  sb[9]);  pb1.y = pack_bf16x2(sb[10], sb[11]);
        pb1.z = pack_bf16x2(sb[12], sb[13]); pb1.w = pack_bf16x2(sb[14], sb[15]);

        o = __builtin_amdgcn_mfma_f32_32x32x16_bf16(vfA0, __builtin_bit_cast(bf16x8, pa0), o, 0, 0, 0);
        o = __builtin_amdgcn_mfma_f32_32x32x16_bf16(vfA1, __builtin_bit_cast(bf16x8, pa1), o, 0, 0, 0);
        o = __builtin_amdgcn_mfma_f32_32x32x16_bf16(vfB0, __builtin_bit_cast(bf16x8, pb0), o, 0, 0, 0);
        o = __builtin_amdgcn_mfma_f32_32x32x16_bf16(vfB1, __builtin_bit_cast(bf16x8, pb1), o, 0, 0, 0);
    }

#pragma unroll
    for (int r = 0; r < 16; ++r) {
        int d = (r & 3) + 8 * (r >> 2) + 4 * hi;
        o_lds[w][d][col] = o[r];
    }
    if (hi == 0) { m_lds[w][col] = m_run; l_lds[w][col] = l_run; }
    __syncthreads();

    {
        const int qq = tid & 31;
        const int d0 = tid >> 5;          // 0..15
        float ms[SPLITS];
        float mstar = -3e38f;
#pragma unroll
        for (int s = 0; s < SPLITS; ++s) { ms[s] = m_lds[s][qq]; mstar = fmaxf(mstar, ms[s]); }
        float wn[SPLITS];
        float den = 0.f;
#pragma unroll
        for (int s = 0; s < SPLITS; ++s) {
            wn[s] = exp2f(ms[s] - mstar);
            den = fmaf(wn[s], l_lds[s][qq], den);
        }
        float inv = 1.f / den;
#pragma unroll
        for (int s = 0; s < SPLITS; ++s) wn[s] *= inv;
#pragma unroll
        for (int dd = 0; dd < 2; ++dd) {
            int d = d0 + 16 * dd;
            float a2 = 0.f;
#pragma unroll
            for (int s = 0; s < SPLITS; ++s) a2 = fmaf(wn[s], o_lds[s][d][qq], a2);
            agg[((size_t)b * CLD + d) * NDIM + q0 + qq] = a2;
        }
    }
}

// ---------------- Kernel 3: output projection + BN4 + ReLU + residual ----------------
// (byte-identical to round 8)
__global__ __launch_bounds__(256) void out_proj(
    const float* __restrict__ agg, const float* __restrict__ wo,
    const float* __restrict__ b4s, const float* __restrict__ b4b,
    const float* __restrict__ b4m, const float* __restrict__ b4v,
    const float* __restrict__ x, const float* __restrict__ gamma,
    float* __restrict__ out)
{
    const int tid   = threadIdx.x;
    const int lane  = tid & 63;
    const int b     = blockIdx.y;
    const int w     = __builtin_amdgcn_readfirstlane(tid >> 6);
    const int obase = blockIdx.z * 32 + w * 8;          // uniform
    const int n     = blockIdx.x * 256 + lane * 4;

    float4 acc[8];
#pragma unroll
    for (int o = 0; o < 8; ++o) acc[o] = make_float4(0.f, 0.f, 0.f, 0.f);

    const float* wbase = wo + (size_t)obase * CLD;      // uniform

#pragma unroll 2
    for (int c = 0; c < CLD; c += 4) {
        float4 wq[8];
#pragma unroll
        for (int o = 0; o < 8; ++o)
            wq[o] = *reinterpret_cast<const float4*>(wbase + o * CLD + c);   // s_load
        float4 av[4];
#pragma unroll
        for (int cc = 0; cc < 4; ++cc)
            av[cc] = *reinterpret_cast<const float4*>(agg + ((size_t)b * CLD + c + cc) * NDIM + n);
#pragma unroll
        for (int cc = 0; cc < 4; ++cc) {
#pragma unroll
            for (int o = 0; o < 8; ++o) {
                float wv = (cc == 0) ? wq[o].x : (cc == 1) ? wq[o].y : (cc == 2) ? wq[o].z : wq[o].w;
                acc[o].x = fmaf(wv, av[cc].x, acc[o].x);
                acc[o].y = fmaf(wv, av[cc].y, acc[o].y);
                acc[o].z = fmaf(wv, av[cc].z, acc[o].z);
                acc[o].w = fmaf(wv, av[cc].w, acc[o].w);
            }
        }
    }

    const float gm = gamma[0];
#pragma unroll
    for (int o = 0; o < 8; ++o) {
        int oo = obase + o;
        float inv = b4s[oo] / sqrtf(b4v[oo] + EPSBN);
        float bi  = b4b[oo] - b4m[oo] * inv;
        const size_t idx = ((size_t)b * CDIM + oo) * NDIM + n;
        float4 xv = *reinterpret_cast<const float4*>(x + idx);
        float4 r;
        r.x = fmaf(gm, fmaxf(fmaf(acc[o].x, inv, bi), 0.f), xv.x);
        r.y = fmaf(gm, fmaxf(fmaf(acc[o].y, inv, bi), 0.f), xv.y);
        r.z = fmaf(gm, fmaxf(fmaf(acc[o].z, inv, bi), 0.f), xv.z);
        r.w = fmaf(gm, fmaxf(fmaf(acc[o].w, inv, bi), 0.f), xv.w);
        *reinterpret_cast<float4*>(out + idx) = r;
    }
}

extern "C" void kernel_launch(void* const* d_in, const int* in_sizes, int n_in,
                              void* d_out, int out_size, void* d_ws, size_t ws_size,
                              hipStream_t stream) {
    const float* x   = (const float*)d_in[0];
    const float* w1  = (const float*)d_in[1];
    const float* w2  = (const float*)d_in[2];
    const float* w3  = (const float*)d_in[3];
    const float* wo  = (const float*)d_in[4];
    const float* b1s = (const float*)d_in[5];
    const float* b1b = (const float*)d_in[6];
    const float* b1m = (const float*)d_in[7];
    const float* b1v = (const float*)d_in[8];
    const float* b2s = (const float*)d_in[9];
    const float* b2b = (const float*)d_in[10];
    const float* b2m = (const float*)d_in[11];
    const float* b2v = (const float*)d_in[12];
    const float* b3s = (const float*)d_in[13];
    const float* b3b = (const float*)d_in[14];
    const float* b3m = (const float*)d_in[15];
    const float* b3v = (const float*)d_in[16];
    const float* b4s = (const float*)d_in[17];
    const float* b4b = (const float*)d_in[18];
    const float* b4m = (const float*)d_in[19];
    const float* b4v = (const float*)d_in[20];
    const float* gm  = (const float*)d_in[21];
    float* out = (float*)d_out;

    // ws layout (bytes):
    //   [0, 1MB)   : qbf bf16 [B][N][32]  (pre-scaled by log2e)
    //   [1MB, 2MB) : kbf bf16 [B][N][32]
    //   [2MB, 3MB) : vbf bf16 [B][NT][32d][32slot]  (kappa slot order)
    //   [3MB, 5MB) : agg f32  [B][32][N]
    char* W = (char*)d_ws;
    u16* qbf = (u16*)W;
    u16* kbf = (u16*)(W + (1u << 20));
    u16* vbf = (u16*)(W + (2u << 20));
    float* agg = (float*)(W + (3u << 20));

    dim3 gp(32, 3, BATCH);
    proj_qkv<<<gp, 256, 0, stream>>>(x, w1, w2, w3,
                                     b1s, b1b, b1m, b1v,
                                     b2s, b2b, b2m, b2v,
                                     b3s, b3b, b3m, b3v,
                                     qbf, kbf, vbf);

    dim3 ga(NDIM / 32, BATCH);
    attn_mfma<<<ga, 512, 0, stream>>>(qbf, kbf, vbf, agg);

    dim3 go(NDIM / 256, BATCH, 8);
    out_proj<<<go, 256, 0, stream>>>(agg, wo, b4s, b4b, b4m, b4v, x, gm, out);
}